// Round 1
// baseline (1041.198 us; speedup 1.0000x reference)
//
#include <hip/hip_runtime.h>
#include <cmath>

// Problem constants
constexpr int Bn   = 64;
constexpr int Sn   = 8192;
constexpr int DDEC = 128;
constexpr int DENC = 128;
constexpr int Fn   = 16;
constexpr int Un   = 128;

constexpr int CHUNK  = 32;            // u-tile held in accumulators per phase
constexpr int NPHASE = Un / CHUNK;    // 4
constexpr int ROWS_PER_BLOCK = 512;   // 256 threads x 2 rows

__device__ __forceinline__ float fast_tanh(float x) {
    // tanh(x) = sign(x) * (1 - 2/(exp(2|x|)+1)); exp overflow -> rcp(inf)=0 -> t=1
    float ax = fabsf(x);
    float e  = __expf(2.0f * ax);
    float t  = 1.0f - 2.0f * __builtin_amdgcn_rcpf(e + 1.0f);
    return copysignf(t, x);
}

// float -> order-preserving uint32 (handles negatives incl. -1e9 masked logits)
__device__ __forceinline__ unsigned int fkey(float f) {
    unsigned int u = __float_as_uint(f);
    return (u & 0x80000000u) ? ~u : (u | 0x80000000u);
}

// qq[b][u] = dec[b] @ W1[:,u] + W1_b[u] + W2_b[u]; also zero per-b softmax accumulators.
__global__ void setup_kernel(const float* __restrict__ dec,
                             const float* __restrict__ W1,
                             const float* __restrict__ W1b,
                             const float* __restrict__ W2b,
                             float* __restrict__ qq,
                             float* __restrict__ sums,
                             unsigned long long* __restrict__ amax) {
    int u = threadIdx.x;               // 128 threads
    int b = blockIdx.x;                // 64 blocks
    float acc = W1b[u] + W2b[u];
    #pragma unroll 8
    for (int d = 0; d < DDEC; ++d)
        acc = fmaf(dec[b * DDEC + d], W1[d * Un + u], acc);
    qq[b * Un + u] = acc;
    if (u == 0) { sums[b] = 0.0f; amax[b] = 0ull; }
}

// Main: 256 threads x 2 rows each. u chunked into 4 phases of 32 accumulators;
// W2's 128x32 u-slab staged in LDS (16 KB) per phase, read as wave-uniform
// broadcast ds_read_b128 (conflict-free). e-rows streamed one float4 per 256
// FMAs -> no big register-resident array for the compiler to sink.
// Epilogue fuses exp (fixed max = 10: logits <= 10 by construction, masked
// entries underflow to 0 exactly like exp(x - rowmax) in the reference),
// partial row-sum and partial argmax via wave reduce + one atomic per wave.
__global__ __launch_bounds__(256, 4)
void score_kernel(const float* __restrict__ enc,    // [B,S,DENC]
                  const float* __restrict__ mask,   // [B,S]
                  const float* __restrict__ qq,     // [B,U]
                  const float* __restrict__ W2,     // [DENC,U] (original layout)
                  const float* __restrict__ V,      // [U]
                  const float* __restrict__ Vb,     // [1]
                  float* __restrict__ logits,       // [B,S]
                  float* __restrict__ probs,        // [B,S] (unnormalized here)
                  float* __restrict__ sums,         // [B]
                  unsigned long long* __restrict__ amax) {  // [B]
    __shared__ float wlds[DENC * CHUNK];            // 16 KB: [d][i]
    const int tid  = threadIdx.x;
    const int base = blockIdx.x * ROWS_PER_BLOCK;
    const int r0   = base + tid;
    const int r1   = r0 + 256;
    const int b    = base >> 13;                    // S = 8192; block within one b

    const float4* e0 = (const float4*)(enc + (size_t)r0 * DENC);
    const float4* e1 = (const float4*)(enc + (size_t)r1 * DENC);
    const float*  qrow = qq + b * Un;

    float score0 = Vb[0];
    float score1 = score0;

    for (int c = 0; c < NPHASE; ++c) {
        __syncthreads();                            // all prior-phase LDS reads done
        float4* wv4 = (float4*)wlds;
        #pragma unroll
        for (int it = 0; it < 4; ++it) {            // stage W2[:, c*32 .. +32)
            int idx = tid + it * 256;               // 0..1023 float4 slots
            int d   = idx >> 3;
            int i4  = idx & 7;
            wv4[idx] = *(const float4*)(W2 + d * Un + c * CHUNK + i4 * 4);
        }
        __syncthreads();

        float a0[CHUNK], a1[CHUNK];
        #pragma unroll
        for (int i = 0; i < CHUNK; ++i) {
            float qv = qrow[c * CHUNK + i];
            a0[i] = qv; a1[i] = qv;
        }

        #pragma unroll 2
        for (int dj = 0; dj < DENC / 4; ++dj) {
            float4 ev0 = e0[dj];
            float4 ev1 = e1[dj];
            float ea[4] = {ev0.x, ev0.y, ev0.z, ev0.w};
            float eb[4] = {ev1.x, ev1.y, ev1.z, ev1.w};
            const float4* wrow = (const float4*)wlds + dj * 32;  // 4 d-rows x 8 f4
            #pragma unroll
            for (int dd = 0; dd < 4; ++dd) {
                #pragma unroll
                for (int i4 = 0; i4 < 8; ++i4) {
                    float4 w = wrow[dd * 8 + i4];   // wave-uniform -> LDS broadcast
                    a0[i4*4+0] = fmaf(ea[dd], w.x, a0[i4*4+0]);
                    a0[i4*4+1] = fmaf(ea[dd], w.y, a0[i4*4+1]);
                    a0[i4*4+2] = fmaf(ea[dd], w.z, a0[i4*4+2]);
                    a0[i4*4+3] = fmaf(ea[dd], w.w, a0[i4*4+3]);
                    a1[i4*4+0] = fmaf(eb[dd], w.x, a1[i4*4+0]);
                    a1[i4*4+1] = fmaf(eb[dd], w.y, a1[i4*4+1]);
                    a1[i4*4+2] = fmaf(eb[dd], w.z, a1[i4*4+2]);
                    a1[i4*4+3] = fmaf(eb[dd], w.w, a1[i4*4+3]);
                }
            }
        }

        #pragma unroll
        for (int i = 0; i < CHUNK; ++i) {
            float vv = V[c * CHUNK + i];
            score0 = fmaf(fast_tanh(a0[i]), vv, score0);
            score1 = fmaf(fast_tanh(a1[i]), vv, score1);
        }
    }

    float l0 = 10.0f * fast_tanh(score0) - mask[r0] * 1e9f;
    float l1 = 10.0f * fast_tanh(score1) - mask[r1] * 1e9f;
    logits[r0] = l0;
    logits[r1] = l1;

    // exp with fixed max=10 (logit <= 10 always; masked -> exp(-1e9) -> 0)
    float p0 = __expf(l0 - 10.0f);
    float p1 = __expf(l1 - 10.0f);
    probs[r0] = p0;
    probs[r1] = p1;

    // wave-level partial reductions -> one atomic per wave per b
    float ps = p0 + p1;
    unsigned long long k0 =
        ((unsigned long long)fkey(l0) << 32) | (unsigned int)(Sn - 1 - (r0 & (Sn - 1)));
    unsigned long long k1 =
        ((unsigned long long)fkey(l1) << 32) | (unsigned int)(Sn - 1 - (r1 & (Sn - 1)));
    unsigned long long key = (k0 > k1) ? k0 : k1;   // equal key -> larger low word = smaller s
    #pragma unroll
    for (int off = 1; off < 64; off <<= 1) {
        ps += __shfl_xor(ps, off);
        unsigned long long ok = __shfl_xor(key, off);
        if (ok > key) key = ok;
    }
    if ((tid & 63) == 0) {
        atomicAdd(&sums[b], ps);
        atomicMax(&amax[b], key);
    }
}

// Full-width normalize + tiny tail block for index/gather.
__global__ __launch_bounds__(256)
void finalize_kernel(const float* __restrict__ enc_in,   // [B,S,F]
                     const float* __restrict__ sums,     // [B]
                     const unsigned long long* __restrict__ amax,  // [B]
                     float* __restrict__ probs,          // [B,S] in-place scale
                     float* __restrict__ out_idx,        // [B] (as float)
                     float* __restrict__ out_gath) {     // [B,F]
    int blk = blockIdx.x;
    int tid = threadIdx.x;
    if (blk < (Bn * Sn) / 256) {
        int row = blk * 256 + tid;
        int b = row >> 13;
        probs[row] *= 1.0f / sums[b];
        return;
    }
    // tail block: pointer_index + gather
    for (int i = tid; i < Bn * Fn; i += 256) {
        int b = i >> 4, f = i & (Fn - 1);
        int I = Sn - 1 - (int)(amax[b] & 0xFFFFFFFFull);
        out_gath[i] = enc_in[((size_t)b * Sn + I) * Fn + f];
    }
    if (tid < Bn) {
        int I = Sn - 1 - (int)(amax[tid] & 0xFFFFFFFFull);
        out_idx[tid] = (float)I;
    }
}

extern "C" void kernel_launch(void* const* d_in, const int* in_sizes, int n_in,
                              void* d_out, int out_size, void* d_ws, size_t ws_size,
                              hipStream_t stream) {
    const float* dec    = (const float*)d_in[0];  // [B,1,DDEC]
    const float* enc_in = (const float*)d_in[1];  // [B,S,F]
    const float* enc    = (const float*)d_in[2];  // [B,S,DENC]
    const float* mask   = (const float*)d_in[3];  // [B,S]
    const float* W1     = (const float*)d_in[4];  // [DDEC,U]
    const float* W1b    = (const float*)d_in[5];  // [U]
    const float* W2     = (const float*)d_in[6];  // [DENC,U]
    const float* W2b    = (const float*)d_in[7];  // [U]
    const float* V      = (const float*)d_in[8];  // [U,1]
    const float* Vb     = (const float*)d_in[9];  // [1]

    float* qq   = (float*)d_ws;                       // B*U floats
    float* sums = qq + Bn * Un;                       // B floats
    unsigned long long* amax =
        (unsigned long long*)(sums + Bn);             // B u64 (8B-aligned: 33024 % 8 == 0)

    float* logits = (float*)d_out;                    // [B,S]
    float* probs  = logits + (size_t)Bn * Sn;         // [B,S]
    float* oidx   = probs + (size_t)Bn * Sn;          // [B]
    float* ogath  = oidx + Bn;                        // [B,F]

    setup_kernel<<<Bn, 128, 0, stream>>>(dec, W1, W1b, W2b, qq, sums, amax);
    score_kernel<<<(Bn * Sn) / ROWS_PER_BLOCK, 256, 0, stream>>>(
        enc, mask, qq, W2, V, Vb, logits, probs, sums, amax);
    finalize_kernel<<<(Bn * Sn) / 256 + 1, 256, 0, stream>>>(
        enc_in, sums, amax, probs, oidx, ogath);
}

// Round 2
// 844.631 us; speedup vs baseline: 1.2327x; 1.2327x over previous
//
#include <hip/hip_runtime.h>
#include <cmath>

// Problem constants
constexpr int Bn   = 64;
constexpr int Sn   = 8192;
constexpr int DDEC = 128;
constexpr int DENC = 128;
constexpr int Fn   = 16;
constexpr int Un   = 128;

__device__ __forceinline__ float fast_tanh(float x) {
    // tanh(x) = sign(x) * (1 - 2/(exp(2|x|)+1)); exp overflow -> rcp(inf)=0 -> t=1
    float ax = fabsf(x);
    float e  = __expf(2.0f * ax);
    float t  = 1.0f - 2.0f * __builtin_amdgcn_rcpf(e + 1.0f);
    return copysignf(t, x);
}

// float -> order-preserving uint32 (handles negatives incl. -1e9 masked logits)
__device__ __forceinline__ unsigned int fkey(float f) {
    unsigned int u = __float_as_uint(f);
    return (u & 0x80000000u) ? ~u : (u | 0x80000000u);
}

// Setup: qq[b][u] = dec[b]@W1[:,u] + W1_b[u] + W2_b[u]  (W2 bias folded in)
//        w2t[u][d] = W2[d][u]  (u-major, staged into LDS by score_kernel)
//        zero the per-b softmax accumulators.
__global__ void setup_kernel(const float* __restrict__ dec,
                             const float* __restrict__ W1,
                             const float* __restrict__ W1b,
                             const float* __restrict__ W2,
                             const float* __restrict__ W2b,
                             float* __restrict__ qq,
                             float* __restrict__ w2t,
                             float* __restrict__ sums,
                             unsigned long long* __restrict__ amax) {
    int u = threadIdx.x;           // 128 threads
    int blk = blockIdx.x;
    if (blk < Bn) {
        int b = blk;
        float acc = W1b[u] + W2b[u];
        #pragma unroll 8
        for (int d = 0; d < DDEC; ++d)
            acc = fmaf(dec[b * DDEC + d], W1[d * Un + u], acc);
        qq[b * Un + u] = acc;
        if (u == 0) { sums[b] = 0.0f; amax[b] = 0ull; }
    } else {
        for (int d = 0; d < DENC; ++d)
            w2t[u * DENC + d] = W2[d * Un + u];
    }
}

// Main: one (b,s) row per thread. The 512 B enc row is FORCED register-resident
// (asm pin: the empty asm consumes+redefines each component, so the compiler
// cannot sink the loads into the u-loop -- the round-0 failure at VGPR=72).
// Accumulators are only 4 floats (round-1's 64-float tile spilled -> 2.6 GB
// scratch traffic). W2^T (64 KB) staged once into LDS via linear float4 copy
// (contiguous wave writes = conflict-free); inner loop reads it as wave-uniform
// ds_read_b128 broadcasts (conflict-free). 64 KB LDS -> 2 blocks/CU; VGPR ~180
// under the (256,2) budget -> 2 waves/SIMD -> 8 waves/CU.
// Epilogue fuses exp (fixed max = 10: logit <= 10 by construction; masked rows
// underflow to exactly 0), per-wave sum + first-occurrence argmax reduction,
// one atomicAdd + one atomicMax per wave.
__global__ __launch_bounds__(256, 2)
void score_kernel(const float* __restrict__ enc,    // [B,S,DENC]
                  const float* __restrict__ mask,   // [B,S]
                  const float* __restrict__ qq,     // [B,U]
                  const float* __restrict__ w2t,    // [U,DENC] u-major
                  const float* __restrict__ V,      // [U]
                  const float* __restrict__ Vb,     // [1]
                  float* __restrict__ logits,       // [B,S]
                  float* __restrict__ probs,        // [B,S] (unnormalized here)
                  float* __restrict__ sums,         // [B]
                  unsigned long long* __restrict__ amax) {  // [B]
    __shared__ float wlds[Un * DENC];               // 64 KB, [u][d] stride 128
    const int tid  = threadIdx.x;
    const int base = blockIdx.x * 256;
    const int row  = base + tid;
    const int b    = base >> 13;                    // S = 8192; b uniform per block

    // Stage w2t -> LDS: linear float4 copy, coalesced global, conflict-free LDS.
    {
        const float4* src = (const float4*)w2t;
        float4* dst = (float4*)wlds;
        #pragma unroll
        for (int it = 0; it < 16; ++it)
            dst[tid + it * 256] = src[tid + it * 256];
    }

    // Load this row's 512 B into registers and pin them there.
    const float4* erow = (const float4*)(enc + (size_t)row * DENC);
    float4 e[32];
    #pragma unroll
    for (int j = 0; j < 32; ++j) e[j] = erow[j];
    #pragma unroll
    for (int j = 0; j < 32; ++j)
        asm volatile("" : "+v"(e[j].x), "+v"(e[j].y), "+v"(e[j].z), "+v"(e[j].w));

    __syncthreads();

    const float* qrow = qq + b * Un;                // uniform -> s_load
    float score = Vb[0];

    #pragma unroll 2
    for (int u = 0; u < Un; ++u) {
        const float4* w = (const float4*)(wlds + u * DENC);
        // 4 independent partials: break the fma dep chain (4-cyc latency vs
        // 2-cyc issue) so 2 waves/SIMD sustain full fp32 issue rate.
        float k0 = qrow[u], k1 = 0.0f, k2 = 0.0f, k3 = 0.0f;
        #pragma unroll
        for (int j = 0; j < 32; j += 4) {
            float4 w0 = w[j], w1 = w[j+1], w2 = w[j+2], w3 = w[j+3];
            k0 = fmaf(e[j  ].x, w0.x, k0); k0 = fmaf(e[j  ].y, w0.y, k0);
            k0 = fmaf(e[j  ].z, w0.z, k0); k0 = fmaf(e[j  ].w, w0.w, k0);
            k1 = fmaf(e[j+1].x, w1.x, k1); k1 = fmaf(e[j+1].y, w1.y, k1);
            k1 = fmaf(e[j+1].z, w1.z, k1); k1 = fmaf(e[j+1].w, w1.w, k1);
            k2 = fmaf(e[j+2].x, w2.x, k2); k2 = fmaf(e[j+2].y, w2.y, k2);
            k2 = fmaf(e[j+2].z, w2.z, k2); k2 = fmaf(e[j+2].w, w2.w, k2);
            k3 = fmaf(e[j+3].x, w3.x, k3); k3 = fmaf(e[j+3].y, w3.y, k3);
            k3 = fmaf(e[j+3].z, w3.z, k3); k3 = fmaf(e[j+3].w, w3.w, k3);
        }
        float k = (k0 + k1) + (k2 + k3);
        score = fmaf(fast_tanh(k), V[u], score);
    }

    float l = 10.0f * fast_tanh(score) - mask[row] * 1e9f;
    logits[row] = l;

    // exp with fixed max = 10 (logit <= 10 always; masked -> exp(-1e9) -> 0)
    float p = __expf(l - 10.0f);
    probs[row] = p;

    // wave-level partial reductions -> one atomic per wave
    float ps = p;
    unsigned long long key =
        ((unsigned long long)fkey(l) << 32) | (unsigned int)(Sn - 1 - (row & (Sn - 1)));
    #pragma unroll
    for (int off = 1; off < 64; off <<= 1) {
        ps += __shfl_xor(ps, off);
        unsigned long long ok = __shfl_xor(key, off);
        if (ok > key) key = ok;                     // equal logit -> larger low = smaller s
    }
    if ((tid & 63) == 0) {
        atomicAdd(&sums[b], ps);
        atomicMax(&amax[b], key);
    }
}

// Full-width normalize + tiny tail block for index/gather.
__global__ __launch_bounds__(256)
void finalize_kernel(const float* __restrict__ enc_in,   // [B,S,F]
                     const float* __restrict__ sums,     // [B]
                     const unsigned long long* __restrict__ amax,  // [B]
                     float* __restrict__ probs,          // [B,S] in-place scale
                     float* __restrict__ out_idx,        // [B] (as float)
                     float* __restrict__ out_gath) {     // [B,F]
    int blk = blockIdx.x;
    int tid = threadIdx.x;
    if (blk < (Bn * Sn) / 256) {
        int row = blk * 256 + tid;
        int b = row >> 13;
        probs[row] *= 1.0f / sums[b];
        return;
    }
    // tail block: pointer_index + gather
    for (int i = tid; i < Bn * Fn; i += 256) {
        int b = i >> 4, f = i & (Fn - 1);
        int I = Sn - 1 - (int)(amax[b] & 0xFFFFFFFFull);
        out_gath[i] = enc_in[((size_t)b * Sn + I) * Fn + f];
    }
    if (tid < Bn) {
        int I = Sn - 1 - (int)(amax[tid] & 0xFFFFFFFFull);
        out_idx[tid] = (float)I;
    }
}

extern "C" void kernel_launch(void* const* d_in, const int* in_sizes, int n_in,
                              void* d_out, int out_size, void* d_ws, size_t ws_size,
                              hipStream_t stream) {
    const float* dec    = (const float*)d_in[0];  // [B,1,DDEC]
    const float* enc_in = (const float*)d_in[1];  // [B,S,F]
    const float* enc    = (const float*)d_in[2];  // [B,S,DENC]
    const float* mask   = (const float*)d_in[3];  // [B,S]
    const float* W1     = (const float*)d_in[4];  // [DDEC,U]
    const float* W1b    = (const float*)d_in[5];  // [U]
    const float* W2     = (const float*)d_in[6];  // [DENC,U]
    const float* W2b    = (const float*)d_in[7];  // [U]
    const float* V      = (const float*)d_in[8];  // [U,1]
    const float* Vb     = (const float*)d_in[9];  // [1]

    float* qq   = (float*)d_ws;                       // B*U floats
    float* w2t  = qq + Bn * Un;                       // U*DENC floats
    float* sums = w2t + Un * DENC;                    // B floats
    unsigned long long* amax =
        (unsigned long long*)(sums + Bn);             // B u64 (8B aligned)

    float* logits = (float*)d_out;                    // [B,S]
    float* probs  = logits + (size_t)Bn * Sn;         // [B,S]
    float* oidx   = probs + (size_t)Bn * Sn;          // [B]
    float* ogath  = oidx + Bn;                        // [B,F]

    setup_kernel<<<Bn + 1, 128, 0, stream>>>(dec, W1, W1b, W2, W2b, qq, w2t, sums, amax);
    score_kernel<<<(Bn * Sn) / 256, 256, 0, stream>>>(
        enc, mask, qq, w2t, V, Vb, logits, probs, sums, amax);
    finalize_kernel<<<(Bn * Sn) / 256 + 1, 256, 0, stream>>>(
        enc_in, sums, amax, probs, oidx, ogath);
}

// Round 3
// 442.480 us; speedup vs baseline: 2.3531x; 1.9089x over previous
//
#include <hip/hip_runtime.h>
#include <cmath>

// Problem constants
constexpr int Bn   = 64;
constexpr int Sn   = 8192;
constexpr int DDEC = 128;
constexpr int DENC = 128;
constexpr int Fn   = 16;
constexpr int Un   = 128;

using bf16x8 = __attribute__((ext_vector_type(8))) short;
using f32x4  = __attribute__((ext_vector_type(4))) float;

__device__ __forceinline__ float fast_tanh(float x) {
    float ax = fabsf(x);
    float e  = __expf(2.0f * ax);
    float t  = 1.0f - 2.0f * __builtin_amdgcn_rcpf(e + 1.0f);
    return copysignf(t, x);
}

__device__ __forceinline__ unsigned int fkey(float f) {
    unsigned int u = __float_as_uint(f);
    return (u & 0x80000000u) ? ~u : (u | 0x80000000u);
}

__device__ __forceinline__ unsigned int bf16_rne(float f) {
    unsigned int u = __float_as_uint(f);
    return (u + 0x7FFFu + ((u >> 16) & 1u)) >> 16;
}

// Blocks 0..63: qq[b][u] = dec[b]@W1[:,u] + W1_b[u] + W2_b[u]; init sums/amax.
// Blocks 64..71: build bf16 B-fragment table for W2:
//   wftab[(n*4+c)*64 + lane] = 8 RNE-bf16 of W2[d][u], d=c*32+(lane>>4)*8+t, u=n*16+(lane&15)
__global__ void setup_kernel(const float* __restrict__ dec,
                             const float* __restrict__ W1,
                             const float* __restrict__ W1b,
                             const float* __restrict__ W2,
                             const float* __restrict__ W2b,
                             float* __restrict__ qq,
                             uint4* __restrict__ wftab,
                             float* __restrict__ sums,
                             unsigned long long* __restrict__ amax) {
    int blk = blockIdx.x, tid = threadIdx.x;
    if (blk < Bn) {
        if (tid < Un) {
            int b = blk, u = tid;
            float acc = W1b[u] + W2b[u];
            #pragma unroll 8
            for (int d = 0; d < DDEC; ++d)
                acc = fmaf(dec[b * DDEC + d], W1[d * Un + u], acc);
            qq[b * Un + u] = acc;
        }
        if (tid == 0) { sums[blk] = 0.0f; amax[blk] = 0ull; }
    } else {
        int n = blk - Bn;            // u-block 0..7
        int c = tid >> 6;            // k-chunk 0..3
        int lane = tid & 63;
        int d0 = c * 32 + (lane >> 4) * 8;
        int u  = n * 16 + (lane & 15);
        unsigned int r[8];
        #pragma unroll
        for (int t = 0; t < 8; ++t)
            r[t] = bf16_rne(W2[(d0 + t) * Un + u]);
        uint4 out;
        out.x = r[0] | (r[1] << 16);
        out.y = r[2] | (r[3] << 16);
        out.z = r[4] | (r[5] << 16);
        out.w = r[6] | (r[7] << 16);
        wftab[(n * 4 + c) * 64 + lane] = out;
    }
}

// Split 8 fp32 (two float4, k-order) into hi/lo bf16x8 fragments.
// hi = truncation; lo = truncation of (f - hi): combined ~2^-17 relative.
__device__ __forceinline__ void cvt_hilo(float4 a, float4 b, uint4& hi, uint4& lo) {
    unsigned int ua[8] = { __float_as_uint(a.x), __float_as_uint(a.y),
                           __float_as_uint(a.z), __float_as_uint(a.w),
                           __float_as_uint(b.x), __float_as_uint(b.y),
                           __float_as_uint(b.z), __float_as_uint(b.w) };
    float fa[8] = { a.x, a.y, a.z, a.w, b.x, b.y, b.z, b.w };
    unsigned int vl[8];
    #pragma unroll
    for (int j = 0; j < 8; ++j) {
        float hf = __uint_as_float(ua[j] & 0xFFFF0000u);
        vl[j] = __float_as_uint(fa[j] - hf);
    }
    hi.x = (ua[1] & 0xFFFF0000u) | (ua[0] >> 16);
    hi.y = (ua[3] & 0xFFFF0000u) | (ua[2] >> 16);
    hi.z = (ua[5] & 0xFFFF0000u) | (ua[4] >> 16);
    hi.w = (ua[7] & 0xFFFF0000u) | (ua[6] >> 16);
    lo.x = (vl[1] & 0xFFFF0000u) | (vl[0] >> 16);
    lo.y = (vl[3] & 0xFFFF0000u) | (vl[2] >> 16);
    lo.z = (vl[5] & 0xFFFF0000u) | (vl[4] >> 16);
    lo.w = (vl[7] & 0xFFFF0000u) | (vl[6] >> 16);
}

// MFMA score kernel: each wave owns 256 rows (16 subtiles of 16 rows).
// W2 bf16 fragments: 32 uint4 = 128 VGPR, register-resident, loaded ONCE per
// wave (kills rounds 0/2's per-tile weight re-read). enc hi/lo bf16 split ->
// 2 MFMAs per (u-block, k-chunk): 64 mfma_f32_16x16x32_bf16 per subtile.
// No LDS. Next subtile's 8 fragment loads issue before the epilogue (tanh,
// V-dot, 16-lane shuffle reduce, exp, softmax partials) -> latency hidden.
__global__ __launch_bounds__(256, 2)
void score_kernel(const float* __restrict__ enc,    // [B,S,DENC]
                  const float* __restrict__ mask,   // [B,S]
                  const float* __restrict__ qq,     // [B,U]
                  const uint4* __restrict__ wftab,  // [8][4][64]
                  const float* __restrict__ V,      // [U]
                  const float* __restrict__ Vb,     // [1]
                  float* __restrict__ logits,       // [B,S]
                  float* __restrict__ probs,        // [B,S] unnormalized
                  float* __restrict__ sums,         // [B]
                  unsigned long long* __restrict__ amax) {  // [B]
    const int tid  = threadIdx.x;
    const int lane = tid & 63;
    const int wv   = tid >> 6;
    const int wave_id = blockIdx.x * 4 + wv;        // 0..2047
    const int base = wave_id * 256;                 // first row of this wave
    const int b    = base >> 13;                    // uniform per wave
    const int g    = lane >> 4;                     // k-group / row-quad
    const int li   = lane & 15;

    // W fragments: resident for the whole kernel.
    uint4 wf[32];
    #pragma unroll
    for (int i = 0; i < 32; ++i) wf[i] = wftab[i * 64 + lane];

    float qv[8], Vl[8];
    #pragma unroll
    for (int n = 0; n < 8; ++n) {
        qv[n] = qq[b * Un + n * 16 + li];
        Vl[n] = V[n * 16 + li];
    }
    const float Vbias = Vb[0];
    const bool active = (li < 4);

    const float4* eptr = (const float4*)enc;
    // fragment float4 index for subtile st: (base+st*16+li)*32 + g*2 + c*8 + h
    float4 ebuf[8];
    {
        size_t i0 = (size_t)(base + li) * 32 + g * 2;
        #pragma unroll
        for (int c = 0; c < 4; ++c) {
            ebuf[2 * c]     = eptr[i0 + c * 8];
            ebuf[2 * c + 1] = eptr[i0 + c * 8 + 1];
        }
    }

    float psum = 0.0f;
    unsigned long long key = 0ull;

    #pragma unroll 1
    for (int st = 0; st < 16; ++st) {
        const int myrow = base + st * 16 + 4 * g + li;   // epilogue row (active only)
        float mval = 0.0f;
        if (active) mval = mask[myrow];                   // issued early, used late

        f32x4 acc[8];
        #pragma unroll
        for (int n = 0; n < 8; ++n)
            acc[n] = f32x4{qv[n], qv[n], qv[n], qv[n]};

        #pragma unroll
        for (int c = 0; c < 4; ++c) {
            uint4 hi, lo;
            cvt_hilo(ebuf[2 * c], ebuf[2 * c + 1], hi, lo);
            bf16x8 ah = __builtin_bit_cast(bf16x8, hi);
            bf16x8 al = __builtin_bit_cast(bf16x8, lo);
            #pragma unroll
            for (int n = 0; n < 8; ++n)
                acc[n] = __builtin_amdgcn_mfma_f32_16x16x32_bf16(
                    ah, __builtin_bit_cast(bf16x8, wf[n * 4 + c]), acc[n], 0, 0, 0);
            #pragma unroll
            for (int n = 0; n < 8; ++n)
                acc[n] = __builtin_amdgcn_mfma_f32_16x16x32_bf16(
                    al, __builtin_bit_cast(bf16x8, wf[n * 4 + c]), acc[n], 0, 0, 0);
        }

        // Issue next subtile's loads before the epilogue (latency hiding).
        if (st < 15) {
            size_t i0 = (size_t)(base + (st + 1) * 16 + li) * 32 + g * 2;
            #pragma unroll
            for (int c = 0; c < 4; ++c) {
                ebuf[2 * c]     = eptr[i0 + c * 8];
                ebuf[2 * c + 1] = eptr[i0 + c * 8 + 1];
            }
        }

        // Epilogue: tanh + V-dot. Lane holds rows 4g+0..3 (regs) x col li.
        float pr0 = 0.0f, pr1 = 0.0f, pr2 = 0.0f, pr3 = 0.0f;
        #pragma unroll
        for (int n = 0; n < 8; ++n) {
            pr0 = fmaf(fast_tanh(acc[n][0]), Vl[n], pr0);
            pr1 = fmaf(fast_tanh(acc[n][1]), Vl[n], pr1);
            pr2 = fmaf(fast_tanh(acc[n][2]), Vl[n], pr2);
            pr3 = fmaf(fast_tanh(acc[n][3]), Vl[n], pr3);
        }
        #pragma unroll
        for (int off = 1; off < 16; off <<= 1) {
            pr0 += __shfl_xor(pr0, off);
            pr1 += __shfl_xor(pr1, off);
            pr2 += __shfl_xor(pr2, off);
            pr3 += __shfl_xor(pr3, off);
        }
        if (active) {
            float sc = (li == 0) ? pr0 : (li == 1) ? pr1 : (li == 2) ? pr2 : pr3;
            sc += Vbias;
            float l = 10.0f * fast_tanh(sc) - mval * 1e9f;
            logits[myrow] = l;
            float p = __expf(l - 10.0f);   // fixed max=10: logit<=10 always
            probs[myrow] = p;
            psum += p;
            unsigned long long k =
                ((unsigned long long)fkey(l) << 32) |
                (unsigned int)(Sn - 1 - (myrow & (Sn - 1)));
            if (k > key) key = k;
        }
    }

    #pragma unroll
    for (int off = 1; off < 64; off <<= 1) {
        psum += __shfl_xor(psum, off);
        unsigned long long ok = __shfl_xor(key, off);
        if (ok > key) key = ok;
    }
    if (lane == 0) {
        atomicAdd(&sums[b], psum);
        atomicMax(&amax[b], key);
    }
}

// Exact-argmax repair: collect rows within 0.125 of the approx max (bf16 logit
// error is ~1.5e-3 rms, <<0.125 bound), recompute their logits exactly in fp32
// (same math as rounds 0-2), pick first-occurrence max, gather.
__global__ __launch_bounds__(256)
void argfix_kernel(const float* __restrict__ logits,
                   const float* __restrict__ enc,
                   const float* __restrict__ qq,
                   const float* __restrict__ W2,
                   const float* __restrict__ V,
                   const float* __restrict__ Vb,
                   const float* __restrict__ enc_in,
                   const unsigned long long* __restrict__ amax,
                   float* __restrict__ out_idx,
                   float* __restrict__ out_gath) {
    int b = blockIdx.x, tid = threadIdx.x;
    __shared__ int cnt;
    __shared__ int cand[64];
    __shared__ float red[256];
    __shared__ float bestL;
    __shared__ int bestI;
    if (tid == 0) { cnt = 0; bestL = -INFINITY; bestI = 0x7fffffff; }
    __syncthreads();

    unsigned int hk = (unsigned int)(amax[b] >> 32);
    float M = (hk & 0x80000000u) ? __uint_as_float(hk & 0x7FFFFFFFu)
                                 : __uint_as_float(~hk);
    const float* lrow = logits + (size_t)b * Sn;
    for (int s = tid; s < Sn; s += 256) {
        if (lrow[s] >= M - 0.125f) {
            int i = atomicAdd(&cnt, 1);
            if (i < 64) cand[i] = s;
        }
    }
    __syncthreads();
    int n = min(cnt, 64);
    int u = tid & 127, h = tid >> 7;

    for (int c = 0; c < n; ++c) {
        int row_s = cand[c];
        const float* erow = enc + ((size_t)b * Sn + row_s) * DENC;
        float kp = 0.0f;
        #pragma unroll 8
        for (int dd = 0; dd < 64; ++dd) {
            int d = h * 64 + dd;
            kp = fmaf(erow[d], W2[d * Un + u], kp);
        }
        red[tid] = kp;
        __syncthreads();
        if (tid < 128) {
            float kk = red[tid] + red[tid + 128] + qq[b * Un + tid];
            red[tid] = fast_tanh(kk) * V[tid];
        }
        __syncthreads();
        for (int off = 64; off > 0; off >>= 1) {
            if (tid < off) red[tid] += red[tid + off];
            __syncthreads();
        }
        if (tid == 0) {
            float sc = red[0] + Vb[0];
            float l = 10.0f * fast_tanh(sc);
            if (l > bestL || (l == bestL && row_s < bestI)) { bestL = l; bestI = row_s; }
        }
        __syncthreads();
    }

    if (tid == 0) out_idx[b] = (float)bestI;
    __syncthreads();
    if (tid < Fn) out_gath[b * Fn + tid] = enc_in[((size_t)b * Sn + bestI) * Fn + tid];
}

// Normalize probs.
__global__ __launch_bounds__(256)
void finalize_kernel(const float* __restrict__ sums,
                     float* __restrict__ probs) {
    int row = blockIdx.x * 256 + threadIdx.x;
    int b = row >> 13;
    probs[row] *= 1.0f / sums[b];
}

extern "C" void kernel_launch(void* const* d_in, const int* in_sizes, int n_in,
                              void* d_out, int out_size, void* d_ws, size_t ws_size,
                              hipStream_t stream) {
    const float* dec    = (const float*)d_in[0];  // [B,1,DDEC]
    const float* enc_in = (const float*)d_in[1];  // [B,S,F]
    const float* enc    = (const float*)d_in[2];  // [B,S,DENC]
    const float* mask   = (const float*)d_in[3];  // [B,S]
    const float* W1     = (const float*)d_in[4];  // [DDEC,U]
    const float* W1b    = (const float*)d_in[5];  // [U]
    const float* W2     = (const float*)d_in[6];  // [DENC,U]
    const float* W2b    = (const float*)d_in[7];  // [U]
    const float* V      = (const float*)d_in[8];  // [U,1]
    const float* Vb     = (const float*)d_in[9];  // [1]

    float* qq   = (float*)d_ws;                       // 8192 floats (32 KB)
    float* sums = qq + Bn * Un;                       // 64 floats
    unsigned long long* amax =
        (unsigned long long*)(sums + Bn);             // 64 u64 (byte 33024, 8-aligned)
    uint4* wftab = (uint4*)(amax + Bn);               // 32*64 uint4 (byte 33536, 16-aligned)

    float* logits = (float*)d_out;                    // [B,S]
    float* probs  = logits + (size_t)Bn * Sn;         // [B,S]
    float* oidx   = probs + (size_t)Bn * Sn;          // [B]
    float* ogath  = oidx + Bn;                        // [B,F]

    setup_kernel<<<Bn + 8, 256, 0, stream>>>(dec, W1, W1b, W2, W2b, qq, wftab, sums, amax);
    score_kernel<<<(Bn * Sn) / (256 * 4), 256, 0, stream>>>(
        enc, mask, qq, wftab, V, Vb, logits, probs, sums, amax);
    argfix_kernel<<<Bn, 256, 0, stream>>>(
        logits, enc, qq, W2, V, Vb, enc_in, amax, oidx, ogath);
    finalize_kernel<<<(Bn * Sn) / 256, 256, 0, stream>>>(sums, probs);
}

// Round 4
// 439.281 us; speedup vs baseline: 2.3702x; 1.0073x over previous
//
#include <hip/hip_runtime.h>
#include <cmath>

// Problem constants
constexpr int Bn   = 64;
constexpr int Sn   = 8192;
constexpr int DDEC = 128;
constexpr int DENC = 128;
constexpr int Fn   = 16;
constexpr int Un   = 128;

using bf16x8 = __attribute__((ext_vector_type(8))) short;
using f32x4  = __attribute__((ext_vector_type(4))) float;

__device__ __forceinline__ float fast_tanh(float x) {
    float ax = fabsf(x);
    float e  = __expf(2.0f * ax);
    float t  = 1.0f - 2.0f * __builtin_amdgcn_rcpf(e + 1.0f);
    return copysignf(t, x);
}

__device__ __forceinline__ unsigned int fkey(float f) {
    unsigned int u = __float_as_uint(f);
    return (u & 0x80000000u) ? ~u : (u | 0x80000000u);
}

__device__ __forceinline__ unsigned int bf16_rne(float f) {
    unsigned int u = __float_as_uint(f);
    return (u + 0x7FFFu + ((u >> 16) & 1u)) >> 16;
}

// Blocks 0..63: qq[b][u] = dec[b]@W1[:,u] + W1_b[u] + W2_b[u]; init sums/amax.
// Blocks 64..71: build bf16 B-fragment table for W2:
//   wftab[(n*4+c)*64 + lane] = 8 RNE-bf16 of W2[d][u], d=c*32+(lane>>4)*8+t, u=n*16+(lane&15)
__global__ void setup_kernel(const float* __restrict__ dec,
                             const float* __restrict__ W1,
                             const float* __restrict__ W1b,
                             const float* __restrict__ W2,
                             const float* __restrict__ W2b,
                             float* __restrict__ qq,
                             uint4* __restrict__ wftab,
                             float* __restrict__ sums,
                             unsigned long long* __restrict__ amax) {
    int blk = blockIdx.x, tid = threadIdx.x;
    if (blk < Bn) {
        if (tid < Un) {
            int b = blk, u = tid;
            float acc = W1b[u] + W2b[u];
            #pragma unroll 8
            for (int d = 0; d < DDEC; ++d)
                acc = fmaf(dec[b * DDEC + d], W1[d * Un + u], acc);
            qq[b * Un + u] = acc;
        }
        if (tid == 0) { sums[blk] = 0.0f; amax[blk] = 0ull; }
    } else {
        int n = blk - Bn;            // u-block 0..7
        int c = tid >> 6;            // k-chunk 0..3
        int lane = tid & 63;
        int d0 = c * 32 + (lane >> 4) * 8;
        int u  = n * 16 + (lane & 15);
        unsigned int r[8];
        #pragma unroll
        for (int t = 0; t < 8; ++t)
            r[t] = bf16_rne(W2[(d0 + t) * Un + u]);
        uint4 out;
        out.x = r[0] | (r[1] << 16);
        out.y = r[2] | (r[3] << 16);
        out.z = r[4] | (r[5] << 16);
        out.w = r[6] | (r[7] << 16);
        wftab[(n * 4 + c) * 64 + lane] = out;
    }
}

// Split 8 fp32 (two float4, k-order) into hi/lo bf16x8 fragments.
// hi = truncation; lo = truncation of (f - hi): combined ~2^-17 relative.
__device__ __forceinline__ void cvt_hilo(float4 a, float4 b, uint4& hi, uint4& lo) {
    unsigned int ua[8] = { __float_as_uint(a.x), __float_as_uint(a.y),
                           __float_as_uint(a.z), __float_as_uint(a.w),
                           __float_as_uint(b.x), __float_as_uint(b.y),
                           __float_as_uint(b.z), __float_as_uint(b.w) };
    float fa[8] = { a.x, a.y, a.z, a.w, b.x, b.y, b.z, b.w };
    unsigned int vl[8];
    #pragma unroll
    for (int j = 0; j < 8; ++j) {
        float hf = __uint_as_float(ua[j] & 0xFFFF0000u);
        vl[j] = __float_as_uint(fa[j] - hf);
    }
    hi.x = (ua[1] & 0xFFFF0000u) | (ua[0] >> 16);
    hi.y = (ua[3] & 0xFFFF0000u) | (ua[2] >> 16);
    hi.z = (ua[5] & 0xFFFF0000u) | (ua[4] >> 16);
    hi.w = (ua[7] & 0xFFFF0000u) | (ua[6] >> 16);
    lo.x = (vl[1] & 0xFFFF0000u) | (vl[0] >> 16);
    lo.y = (vl[3] & 0xFFFF0000u) | (vl[2] >> 16);
    lo.z = (vl[5] & 0xFFFF0000u) | (vl[4] >> 16);
    lo.w = (vl[7] & 0xFFFF0000u) | (vl[6] >> 16);
}

// MFMA score kernel. Round-4 change: per subtile the order is now
//   cvt(ebuf)->frags  (ebuf dead)  ->  issue st+1 loads into ebuf  ->  MFMA  ->  epilogue
// so the load-to-use distance is MFMA(~320cy) + epilogue(~700cy) >= HBM ~900cy,
// vs round-3's epilogue-only cover. No extra buffers: frags were already
// materialized; peak regs ~254 under the (256,2) cap.
__global__ __launch_bounds__(256, 2)
void score_kernel(const float* __restrict__ enc,    // [B,S,DENC]
                  const float* __restrict__ mask,   // [B,S]
                  const float* __restrict__ qq,     // [B,U]
                  const uint4* __restrict__ wftab,  // [8][4][64]
                  const float* __restrict__ V,      // [U]
                  const float* __restrict__ Vb,     // [1]
                  float* __restrict__ logits,       // [B,S]
                  float* __restrict__ probs,        // [B,S] unnormalized
                  float* __restrict__ sums,         // [B]
                  unsigned long long* __restrict__ amax) {  // [B]
    const int tid  = threadIdx.x;
    const int lane = tid & 63;
    const int wv   = tid >> 6;
    const int wave_id = blockIdx.x * 4 + wv;        // 0..2047
    const int base = wave_id * 256;                 // first row of this wave
    const int b    = base >> 13;                    // uniform per wave
    const int g    = lane >> 4;                     // k-group / row-quad
    const int li   = lane & 15;

    // W fragments: resident for the whole kernel (loaded once per wave).
    uint4 wf[32];
    #pragma unroll
    for (int i = 0; i < 32; ++i) wf[i] = wftab[i * 64 + lane];

    float qv[8], Vl[8];
    #pragma unroll
    for (int n = 0; n < 8; ++n) {
        qv[n] = qq[b * Un + n * 16 + li];
        Vl[n] = V[n * 16 + li];
    }
    const float Vbias = Vb[0];
    const bool active = (li < 4);

    const float4* eptr = (const float4*)enc;
    float4 ebuf[8];
    {
        size_t i0 = (size_t)(base + li) * 32 + g * 2;
        #pragma unroll
        for (int c = 0; c < 4; ++c) {
            ebuf[2 * c]     = eptr[i0 + c * 8];
            ebuf[2 * c + 1] = eptr[i0 + c * 8 + 1];
        }
    }

    float psum = 0.0f;
    unsigned long long key = 0ull;

    #pragma unroll 1
    for (int st = 0; st < 16; ++st) {
        const int myrow = base + st * 16 + 4 * g + li;
        float mval = 0.0f;
        if (active) mval = mask[myrow];              // issued early, used late

        // 1) convert current subtile -> fragments (ebuf becomes dead)
        uint4 fh[4], fl[4];
        #pragma unroll
        for (int c = 0; c < 4; ++c)
            cvt_hilo(ebuf[2 * c], ebuf[2 * c + 1], fh[c], fl[c]);

        // 2) issue next subtile's loads NOW (covered by MFMA + epilogue)
        if (st < 15) {
            size_t i0 = (size_t)(base + (st + 1) * 16 + li) * 32 + g * 2;
            #pragma unroll
            for (int c = 0; c < 4; ++c) {
                ebuf[2 * c]     = eptr[i0 + c * 8];
                ebuf[2 * c + 1] = eptr[i0 + c * 8 + 1];
            }
        }

        // 3) MFMA block
        f32x4 acc[8];
        #pragma unroll
        for (int n = 0; n < 8; ++n)
            acc[n] = f32x4{qv[n], qv[n], qv[n], qv[n]};
        #pragma unroll
        for (int c = 0; c < 4; ++c) {
            bf16x8 ah = __builtin_bit_cast(bf16x8, fh[c]);
            bf16x8 al = __builtin_bit_cast(bf16x8, fl[c]);
            #pragma unroll
            for (int n = 0; n < 8; ++n)
                acc[n] = __builtin_amdgcn_mfma_f32_16x16x32_bf16(
                    ah, __builtin_bit_cast(bf16x8, wf[n * 4 + c]), acc[n], 0, 0, 0);
            #pragma unroll
            for (int n = 0; n < 8; ++n)
                acc[n] = __builtin_amdgcn_mfma_f32_16x16x32_bf16(
                    al, __builtin_bit_cast(bf16x8, wf[n * 4 + c]), acc[n], 0, 0, 0);
        }

        // 4) epilogue: tanh + V-dot, 16-lane reduce, softmax partials
        float pr0 = 0.0f, pr1 = 0.0f, pr2 = 0.0f, pr3 = 0.0f;
        #pragma unroll
        for (int n = 0; n < 8; ++n) {
            pr0 = fmaf(fast_tanh(acc[n][0]), Vl[n], pr0);
            pr1 = fmaf(fast_tanh(acc[n][1]), Vl[n], pr1);
            pr2 = fmaf(fast_tanh(acc[n][2]), Vl[n], pr2);
            pr3 = fmaf(fast_tanh(acc[n][3]), Vl[n], pr3);
        }
        #pragma unroll
        for (int off = 1; off < 16; off <<= 1) {
            pr0 += __shfl_xor(pr0, off);
            pr1 += __shfl_xor(pr1, off);
            pr2 += __shfl_xor(pr2, off);
            pr3 += __shfl_xor(pr3, off);
        }
        if (active) {
            float sc = (li == 0) ? pr0 : (li == 1) ? pr1 : (li == 2) ? pr2 : pr3;
            sc += Vbias;
            float l = 10.0f * fast_tanh(sc) - mval * 1e9f;
            logits[myrow] = l;
            float p = __expf(l - 10.0f);   // fixed max=10: logit<=10 always
            probs[myrow] = p;
            psum += p;
            unsigned long long k =
                ((unsigned long long)fkey(l) << 32) |
                (unsigned int)(Sn - 1 - (myrow & (Sn - 1)));
            if (k > key) key = k;
        }
    }

    #pragma unroll
    for (int off = 1; off < 64; off <<= 1) {
        psum += __shfl_xor(psum, off);
        unsigned long long ok = __shfl_xor(key, off);
        if (ok > key) key = ok;
    }
    if (lane == 0) {
        atomicAdd(&sums[b], psum);
        atomicMax(&amax[b], key);
    }
}

// Merged: blocks [0,512) normalize probs (float4); blocks [512,576) do the
// exact-argmax repair + gather for b = blk-512.
__global__ __launch_bounds__(256)
void finalize_kernel(const float* __restrict__ logits,
                     const float* __restrict__ enc,
                     const float* __restrict__ qq,
                     const float* __restrict__ W2,
                     const float* __restrict__ V,
                     const float* __restrict__ Vb,
                     const float* __restrict__ enc_in,
                     const float* __restrict__ sums,
                     const unsigned long long* __restrict__ amax,
                     float* __restrict__ probs,
                     float* __restrict__ out_idx,
                     float* __restrict__ out_gath) {
    int blk = blockIdx.x;
    int tid = threadIdx.x;
    if (blk < (Bn * Sn) / (256 * 4)) {
        int i4 = blk * 256 + tid;                   // float4 index
        int b = i4 >> 11;                           // (i4*4)>>13
        float inv = 1.0f / sums[b];
        float4* p4 = (float4*)probs;
        float4 v = p4[i4];
        v.x *= inv; v.y *= inv; v.z *= inv; v.w *= inv;
        p4[i4] = v;
        return;
    }
    int b = blk - (Bn * Sn) / (256 * 4);

    __shared__ int cnt;
    __shared__ int cand[64];
    __shared__ float red[256];
    __shared__ float bestL;
    __shared__ int bestI;
    if (tid == 0) { cnt = 0; bestL = -INFINITY; bestI = 0x7fffffff; }
    __syncthreads();

    unsigned int hk = (unsigned int)(amax[b] >> 32);
    float M = (hk & 0x80000000u) ? __uint_as_float(hk & 0x7FFFFFFFu)
                                 : __uint_as_float(~hk);
    const float* lrow = logits + (size_t)b * Sn;
    for (int s = tid; s < Sn; s += 256) {
        if (lrow[s] >= M - 0.125f) {
            int i = atomicAdd(&cnt, 1);
            if (i < 64) cand[i] = s;
        }
    }
    __syncthreads();
    int n = min(cnt, 64);
    int u = tid & 127, h = tid >> 7;

    for (int c = 0; c < n; ++c) {
        int row_s = cand[c];
        const float* erow = enc + ((size_t)b * Sn + row_s) * DENC;
        float kp = 0.0f;
        #pragma unroll 8
        for (int dd = 0; dd < 64; ++dd) {
            int d = h * 64 + dd;
            kp = fmaf(erow[d], W2[d * Un + u], kp);
        }
        red[tid] = kp;
        __syncthreads();
        if (tid < 128) {
            float kk = red[tid] + red[tid + 128] + qq[b * Un + tid];
            red[tid] = fast_tanh(kk) * V[tid];
        }
        __syncthreads();
        for (int off = 64; off > 0; off >>= 1) {
            if (tid < off) red[tid] += red[tid + off];
            __syncthreads();
        }
        if (tid == 0) {
            float sc = red[0] + Vb[0];
            float l = 10.0f * fast_tanh(sc);
            if (l > bestL || (l == bestL && row_s < bestI)) { bestL = l; bestI = row_s; }
        }
        __syncthreads();
    }

    if (tid == 0) out_idx[b] = (float)bestI;
    __syncthreads();
    if (tid < Fn) out_gath[b * Fn + tid] = enc_in[((size_t)b * Sn + bestI) * Fn + tid];
}

extern "C" void kernel_launch(void* const* d_in, const int* in_sizes, int n_in,
                              void* d_out, int out_size, void* d_ws, size_t ws_size,
                              hipStream_t stream) {
    const float* dec    = (const float*)d_in[0];  // [B,1,DDEC]
    const float* enc_in = (const float*)d_in[1];  // [B,S,F]
    const float* enc    = (const float*)d_in[2];  // [B,S,DENC]
    const float* mask   = (const float*)d_in[3];  // [B,S]
    const float* W1     = (const float*)d_in[4];  // [DDEC,U]
    const float* W1b    = (const float*)d_in[5];  // [U]
    const float* W2     = (const float*)d_in[6];  // [DENC,U]
    const float* W2b    = (const float*)d_in[7];  // [U]
    const float* V      = (const float*)d_in[8];  // [U,1]
    const float* Vb     = (const float*)d_in[9];  // [1]

    float* qq   = (float*)d_ws;                       // 8192 floats (32 KB)
    float* sums = qq + Bn * Un;                       // 64 floats
    unsigned long long* amax =
        (unsigned long long*)(sums + Bn);             // 64 u64 (byte 33024, 8-aligned)
    uint4* wftab = (uint4*)(amax + Bn);               // 32*64 uint4 (byte 33536, 16-aligned)

    float* logits = (float*)d_out;                    // [B,S]
    float* probs  = logits + (size_t)Bn * Sn;         // [B,S]
    float* oidx   = probs + (size_t)Bn * Sn;          // [B]
    float* ogath  = oidx + Bn;                        // [B,F]

    setup_kernel<<<Bn + 8, 256, 0, stream>>>(dec, W1, W1b, W2, W2b, qq, wftab, sums, amax);
    score_kernel<<<(Bn * Sn) / (256 * 4), 256, 0, stream>>>(
        enc, mask, qq, wftab, V, Vb, logits, probs, sums, amax);
    finalize_kernel<<<(Bn * Sn) / (256 * 4) + Bn, 256, 0, stream>>>(
        logits, enc, qq, W2, V, Vb, enc_in, sums, amax, probs, oidx, ogath);
}